// Round 2
// 357.894 us; speedup vs baseline: 1.4965x; 1.4965x over previous
//
#include <hip/hip_runtime.h>
#include <math.h>

#define BB   4096
#define SEQL 168
#define CF   64
#define PREDN 96
#define KK   25
#define NLAG 11
#define LSTR 178            // u16 elements per channel row in LDS (89 dwords, odd -> conflict-free)

// ws layout (float offsets):
// [0,1600)        softmax conv kernels (fp32, [c][25])
// [1600,1888)     Rot unitaries (36 x 8)
// [2048, 51200)   quantum feats (4096 x 12)
// [51200, 69632)  swizzled bf16 weights (36864 u16): [mat][nt6][ks6][lane64][j8]
#define WS_KER   0
#define WS_U     1600
#define WS_FEATS 2048
#define WS_SWZ   51200

typedef __attribute__((ext_vector_type(8))) short short8;
typedef __attribute__((ext_vector_type(4))) float f32x4;

__device__ __forceinline__ unsigned short f2bf(float f) {
    unsigned int u = __float_as_uint(f);
    u = (u + 0x7FFFu + ((u >> 16) & 1u)) >> 16;   // RNE
    return (unsigned short)u;
}

// ---------------------------------------------------------------- precompute (small)
__global__ void k_pre(const float* __restrict__ decomp_w,
                      const float* __restrict__ wx,
                      const float* __restrict__ wy,
                      const float* __restrict__ wz,
                      float* __restrict__ ws)
{
    int tid = threadIdx.x;
    if (tid < 64) {
        float v[KK]; float mx = -1e30f;
        #pragma unroll
        for (int k = 0; k < KK; ++k) { v[k] = decomp_w[tid*KK + k]; mx = fmaxf(mx, v[k]); }
        float s = 0.f;
        #pragma unroll
        for (int k = 0; k < KK; ++k) { v[k] = expf(v[k] - mx); s += v[k]; }
        float inv = 1.f / s;
        #pragma unroll
        for (int k = 0; k < KK; ++k) ws[WS_KER + tid*KK + k] = v[k]*inv;
    } else if (tid < 64 + 36) {
        int i = tid - 64;
        int circ = i / 12, r = i % 12;
        const float* w = (circ == 0) ? wx : (circ == 1 ? wy : wz);
        float phi = w[r*3+0], th = w[r*3+1], om = w[r*3+2];
        float ct = cosf(0.5f*th), st = sinf(0.5f*th);
        float po = 0.5f*(phi+om), pm = 0.5f*(phi-om);
        float cpo = cosf(po), spo = sinf(po);
        float cpm = cosf(pm), spm = sinf(pm);
        float* U = ws + WS_U + i*8;
        U[0] =  cpo*ct; U[1] = -spo*ct;
        U[2] = -cpm*st; U[3] = -spm*st;
        U[4] =  cpm*st; U[5] = -spm*st;
        U[6] =  cpo*ct; U[7] =  spo*ct;
    }
}

// ---------------------------------------------------------------- weight swizzle (parallel)
__global__ void k_swz(const float* __restrict__ sW,
                      const float* __restrict__ tW,
                      const float* __restrict__ alpha,
                      float* __restrict__ ws)
{
    int idx = blockIdx.x * blockDim.x + threadIdx.x;
    if (idx >= 2*6*6*64*8) return;
    float oma = 1.f - 1.f/(1.f + expf(-alpha[0]));
    unsigned short* wsw = (unsigned short*)(ws + WS_SWZ);
    int j    = idx & 7;
    int lane = (idx >> 3) & 63;
    int rem  = idx >> 9;
    int ks   = rem % 6;
    int nt   = (rem / 6) % 6;
    int mat  = rem / 36;
    int p = nt*16 + (lane & 15);
    int l = ks*32 + ((lane >> 4) & 3)*8 + j;
    float v = 0.f;
    if (l < SEQL) v = mat ? oma * tW[p*SEQL + l] : sW[p*SEQL + l];
    wsw[idx] = f2bf(v);
}

// ---------------------------------------------------------------- quantum feats
// Lane-parallel: 16 lanes per (b,circ) unit, one amplitude per lane.
// Gate pair-partner via __shfl_xor (mask < 16 stays within the unit).
// 196608 threads = 3072 waves (16x the old occupancy).
__global__ void k_quantum(const float* __restrict__ x,
                          const float* __restrict__ lagc_W,
                          const float* __restrict__ lagc_b,
                          const float* __restrict__ ws,
                          float* __restrict__ feats)
{
    int tid  = blockIdx.x * blockDim.x + threadIdx.x;
    int unit = tid >> 4;          // (b, circ)
    int amp  = tid & 15;          // amplitude index, bit (3-q) per qubit q
    int b = unit / 3, circ = unit - b*3;

    const int LAGS[NLAG] = {167,166,165,164,163,162,145,144,143,1,0};
    const float* xb = x + (size_t)b*SEQL*CF + (CF-1);
    float lag[NLAG];
    #pragma unroll
    for (int j = 0; j < NLAG; ++j) lag[j] = xb[LAGS[j]*CF];

    float cq[4], sq[4];
    #pragma unroll
    for (int q = 0; q < 4; ++q) {
        float acc = lagc_b[q];
        #pragma unroll
        for (int j = 0; j < NLAG; ++j) acc = fmaf(lag[j], lagc_W[q*NLAG + j], acc);
        float half = 0.5f * 3.14159265358979323846f * tanhf(acc);
        cq[q] = cosf(half); sq[q] = sinf(half);
    }

    float sr = (amp == 0) ? 1.f : 0.f;
    float si = 0.f;

    const float* Ub = ws + WS_U + circ*96;

    for (int layer = 0; layer < 3; ++layer) {
        // RY(input) on each qubit
        #pragma unroll
        for (int q = 0; q < 4; ++q) {
            int m = 1 << (3-q);
            float pr  = __shfl_xor(sr, m);
            float pii = __shfl_xor(si, m);
            float sel = (amp & m) ? sq[q] : -sq[q];
            sr = fmaf(sel, pr,  cq[q]*sr);
            si = fmaf(sel, pii, cq[q]*si);
        }
        // Rot unitaries
        #pragma unroll
        for (int q = 0; q < 4; ++q) {
            const float* U = Ub + (layer*4 + q)*8;
            int m = 1 << (3-q);
            bool hi = (amp & m) != 0;
            float uar = hi ? U[6] : U[0];   // coeff on own amplitude
            float uai = hi ? U[7] : U[1];
            float ubr = hi ? U[4] : U[2];   // coeff on partner amplitude
            float ubi = hi ? U[5] : U[3];
            float pr  = __shfl_xor(sr, m);
            float pii = __shfl_xor(si, m);
            float nr = uar*sr - uai*si + ubr*pr - ubi*pii;
            float ni = uar*si + uai*sr + ubr*pii + ubi*pr;
            sr = nr; si = ni;
        }
        // CNOT ring
        #pragma unroll
        for (int q = 0; q < 4; ++q) {
            int t  = (q+1) & 3;
            int cm = 1 << (3-q), tm = 1 << (3-t);
            float pr  = __shfl_xor(sr, tm);
            float pii = __shfl_xor(si, tm);
            if (amp & cm) { sr = pr; si = pii; }
        }
    }

    // expvals: per-lane contribution, butterfly-reduce over the 16-lane unit
    #pragma unroll
    for (int q = 0; q < 4; ++q) {
        int m = 1 << (3-q);
        float pr  = __shfl_xor(sr, m);
        float pii = __shfl_xor(si, m);
        float v;
        if (circ == 0) {                       // X: lo+hi both yield a0.a1 -> 2x via sum
            v = sr*pr + si*pii;
        } else if (circ == 1) {                // Y: hi lane contributes negated term
            float t = sr*pii - si*pr;
            v = (amp & m) ? -t : t;
        } else {                               // Z: |lo|^2 - |hi|^2
            float t = sr*sr + si*si;
            v = (amp & m) ? -t : t;
        }
        v += __shfl_xor(v, 1);
        v += __shfl_xor(v, 2);
        v += __shfl_xor(v, 4);
        v += __shfl_xor(v, 8);
        if (amp == 0) feats[b*12 + circ*4 + q] = v;
    }
}

// ---------------------------------------------------------------- fused conv+GEMM (MFMA)
// 1 block = 1 batch row, 256 threads = 4 waves.
// Phase A: sliding-window conv (67 loads/thread instead of 1050 -> kills the L2 storm),
// bf16 T/S written to LDS transposed [c][l] (stride 178).
// Phase B: wave ct handles channels [ct*16, ct*16+16); A-frags via 4x ds_read_b32,
// B-frags from pre-swizzled global table (L2-hot).
__launch_bounds__(256, 3)
__global__ void k_gemm(const float* __restrict__ x,
                       const float* __restrict__ ws,
                       const float* __restrict__ seas_b,
                       const float* __restrict__ trend_b,
                       const float* __restrict__ roW1,
                       const float* __restrict__ rob1,
                       const float* __restrict__ roW2,
                       const float* __restrict__ rob2,
                       const float* __restrict__ alpha,
                       float* __restrict__ out)
{
    __shared__ unsigned short lbuf[2*64*LSTR + 64];   // T | S | slack
    __shared__ float fsL[PREDN];
    __shared__ float cbL[PREDN];

    int b = blockIdx.x;
    int tid = threadIdx.x;

    float a_sig = 1.f / (1.f + expf(-alpha[0]));
    float oma   = 1.f - a_sig;

    // readout MLP -> fs[p], cb[p]
    if (tid < PREDN) {
        const float* f = ws + WS_FEATS + b*12;
        float h[12];
        #pragma unroll
        for (int i = 0; i < 12; ++i) {
            float acc = rob1[i];
            #pragma unroll
            for (int j = 0; j < 12; ++j) acc = fmaf(roW1[i*12+j], f[j], acc);
            h[i] = fmaxf(acc, 0.f);
        }
        float acc = rob2[tid];
        #pragma unroll
        for (int i = 0; i < 12; ++i) acc = fmaf(roW2[tid*12+i], h[i], acc);
        float m   = tanhf(acc);
        float fsv = a_sig * (1.f + m);
        fsL[tid] = fsv;
        cbL[tid] = fsv*seas_b[tid] + oma*trend_b[tid];
    }

    // zero the LDS tail (l in [168,178) for every row, both arrays, + slack):
    // fragment reads touch those slots; B is zero there, values just must be finite.
    for (int i = tid; i < 2*64*10 + 64; i += 256) {
        if (i < 2*64*10) {
            int arr = i / 640;
            int rem = i - arr*640;
            int c   = rem / 10;
            int l   = 168 + rem - c*10;
            lbuf[arr*64*LSTR + c*LSTR + l] = 0;
        } else {
            lbuf[2*64*LSTR + (i - 2*64*10)] = 0;
        }
    }

    // ---- Phase A: sliding-window conv. thread -> (c = tid&63, seg = tid>>6) ----
    {
        int c   = tid & 63;
        int seg = tid >> 6;
        float cf[KK];
        #pragma unroll
        for (int k = 0; k < KK; ++k) cf[k] = ws[WS_KER + c*KK + k];
        const float* xc = x + (size_t)b*SEQL*CF + c;
        unsigned short* lT = lbuf + c*LSTR;
        unsigned short* lS = lbuf + 64*LSTR + c*LSTR;

        int l0 = seg*42;
        float w[KK];
        #pragma unroll
        for (int k = 0; k < KK; ++k) {           // preload window for l = l0 (edge-clamped)
            int ix = l0 + k - 12;
            ix = ix < 0 ? 0 : (ix > SEQL-1 ? SEQL-1 : ix);
            w[k] = xc[ix*CF];
        }
        #pragma unroll
        for (int l = 0; l < 42; ++l) {
            int ll = l0 + l;
            float acc = 0.f;
            #pragma unroll
            for (int k = 0; k < KK; ++k) acc = fmaf(cf[k], w[k], acc);
            lT[ll] = f2bf(acc);
            lS[ll] = f2bf(w[12] - acc);
            #pragma unroll
            for (int k = 0; k < KK-1; ++k) w[k] = w[k+1];   // SSA-renamed, no moves
            int ix = ll + 13;
            ix = ix > SEQL-1 ? SEQL-1 : ix;
            w[KK-1] = xc[ix*CF];
        }
    }
    __syncthreads();

    // ---- Phase B: MFMA GEMM ----
    int lane = tid & 63;
    int ct   = tid >> 6;          // wave id = 16-channel tile
    int mrow = lane & 15;
    int q    = lane >> 4;
    int c    = ct*16 + mrow;

    const unsigned int* L32 = (const unsigned int*)lbuf;
    const int SOFF = 64*LSTR/2;   // dword offset of S array
    const unsigned short* wsw = (const unsigned short*)(ws + WS_SWZ);

    f32x4 accS[6], accT[6];
    #pragma unroll
    for (int nt = 0; nt < 6; ++nt) {
        accS[nt] = (f32x4){0.f,0.f,0.f,0.f};
        accT[nt] = (f32x4){0.f,0.f,0.f,0.f};
    }

    for (int ks = 0; ks < 6; ++ks) {
        int ai = c*(LSTR/2) + ks*16 + q*4;        // dword index of fragment start
        union { unsigned int u[4]; short8 v; } ut, us;
        #pragma unroll
        for (int d = 0; d < 4; ++d) {
            ut.u[d] = L32[ai + d];
            us.u[d] = L32[SOFF + ai + d];
        }
        short8 aT = ut.v, aS = us.v;
        #pragma unroll
        for (int nt = 0; nt < 6; ++nt) {
            short8 Bs = *(const short8*)(wsw + (((0*6 + nt)*6 + ks)*64 + lane)*8);
            short8 Bt = *(const short8*)(wsw + (((1*6 + nt)*6 + ks)*64 + lane)*8);
            accS[nt] = __builtin_amdgcn_mfma_f32_16x16x32_bf16(aS, Bs, accS[nt], 0, 0, 0);
            accT[nt] = __builtin_amdgcn_mfma_f32_16x16x32_bf16(aT, Bt, accT[nt], 0, 0, 0);
        }
    }

    // epilogue: C/D col = lane&15 = p-within-tile, row = q*4+reg = c-within-tile
    #pragma unroll
    for (int nt = 0; nt < 6; ++nt) {
        int p = nt*16 + mrow;
        float fsv = fsL[p];
        float cbv = cbL[p];
        float* og = out + (size_t)b*PREDN*CF + p*CF + ct*16 + (q<<2);
        f32x4 r;
        #pragma unroll
        for (int r4 = 0; r4 < 4; ++r4)
            r[r4] = fmaf(fsv, accS[nt][r4], accT[nt][r4] + cbv);
        *(f32x4*)og = r;
    }
}

// ---------------------------------------------------------------- launch
extern "C" void kernel_launch(void* const* d_in, const int* in_sizes, int n_in,
                              void* d_out, int out_size, void* d_ws, size_t ws_size,
                              hipStream_t stream)
{
    const float* x        = (const float*)d_in[0];
    const float* decomp_w = (const float*)d_in[1];
    const float* trend_W  = (const float*)d_in[2];
    const float* trend_b  = (const float*)d_in[3];
    const float* seas_W   = (const float*)d_in[4];
    const float* seas_b   = (const float*)d_in[5];
    const float* lagc_W   = (const float*)d_in[6];
    const float* lagc_b   = (const float*)d_in[7];
    const float* res_wx   = (const float*)d_in[8];
    const float* res_wy   = (const float*)d_in[9];
    const float* res_wz   = (const float*)d_in[10];
    const float* ro_W1    = (const float*)d_in[11];
    const float* ro_b1    = (const float*)d_in[12];
    const float* ro_W2    = (const float*)d_in[13];
    const float* ro_b2    = (const float*)d_in[14];
    const float* alpha    = (const float*)d_in[15];
    float* out = (float*)d_out;
    float* ws  = (float*)d_ws;

    k_pre<<<1, 128, 0, stream>>>(decomp_w, res_wx, res_wy, res_wz, ws);
    k_swz<<<144, 256, 0, stream>>>(seas_W, trend_W, alpha, ws);
    // 4096*3 units * 16 lanes = 196608 threads = 768 blocks * 256
    k_quantum<<<768, 256, 0, stream>>>(x, lagc_W, lagc_b, ws, ws + WS_FEATS);
    k_gemm<<<BB, 256, 0, stream>>>(x, ws, seas_b, trend_b,
                                   ro_W1, ro_b1, ro_W2, ro_b2, alpha, out);
}

// Round 3
// 343.324 us; speedup vs baseline: 1.5600x; 1.0424x over previous
//
#include <hip/hip_runtime.h>
#include <math.h>

#define BB   4096
#define SEQL 168
#define CF   64
#define PREDN 96
#define KK   25
#define NLAG 11
#define LSTR 178            // u16 elements per channel row in LDS (89 dwords, odd -> conflict-free)

// ws layout (float offsets):
// [0,1600)        softmax conv kernels (fp32, [c][25])
// [1600,1888)     Rot unitaries (36 x 8)
// [2048, 51200)   quantum feats (4096 x 12)
// [51200, 69632)  swizzled bf16 weights (36864 u16): [mat][nt6][ks6][lane64][j8]
#define WS_KER   0
#define WS_U     1600
#define WS_FEATS 2048
#define WS_SWZ   51200

typedef __attribute__((ext_vector_type(8))) short short8;
typedef __attribute__((ext_vector_type(4))) float f32x4;

__device__ __forceinline__ unsigned short f2bf(float f) {
    unsigned int u = __float_as_uint(f);
    u = (u + 0x7FFFu + ((u >> 16) & 1u)) >> 16;   // RNE
    return (unsigned short)u;
}

// ---------------------------------------------------------------- precompute (small)
__global__ void k_pre(const float* __restrict__ decomp_w,
                      const float* __restrict__ wx,
                      const float* __restrict__ wy,
                      const float* __restrict__ wz,
                      float* __restrict__ ws)
{
    int tid = threadIdx.x;
    if (tid < 64) {
        float v[KK]; float mx = -1e30f;
        #pragma unroll
        for (int k = 0; k < KK; ++k) { v[k] = decomp_w[tid*KK + k]; mx = fmaxf(mx, v[k]); }
        float s = 0.f;
        #pragma unroll
        for (int k = 0; k < KK; ++k) { v[k] = expf(v[k] - mx); s += v[k]; }
        float inv = 1.f / s;
        #pragma unroll
        for (int k = 0; k < KK; ++k) ws[WS_KER + tid*KK + k] = v[k]*inv;
    } else if (tid < 64 + 36) {
        int i = tid - 64;
        int circ = i / 12, r = i % 12;
        const float* w = (circ == 0) ? wx : (circ == 1 ? wy : wz);
        float phi = w[r*3+0], th = w[r*3+1], om = w[r*3+2];
        float ct = cosf(0.5f*th), st = sinf(0.5f*th);
        float po = 0.5f*(phi+om), pm = 0.5f*(phi-om);
        float cpo = cosf(po), spo = sinf(po);
        float cpm = cosf(pm), spm = sinf(pm);
        float* U = ws + WS_U + i*8;
        U[0] =  cpo*ct; U[1] = -spo*ct;
        U[2] = -cpm*st; U[3] = -spm*st;
        U[4] =  cpm*st; U[5] = -spm*st;
        U[6] =  cpo*ct; U[7] =  spo*ct;
    }
}

// ---------------------------------------------------------------- weight swizzle (parallel)
__global__ void k_swz(const float* __restrict__ sW,
                      const float* __restrict__ tW,
                      const float* __restrict__ alpha,
                      float* __restrict__ ws)
{
    int idx = blockIdx.x * blockDim.x + threadIdx.x;
    if (idx >= 2*6*6*64*8) return;
    float oma = 1.f - 1.f/(1.f + expf(-alpha[0]));
    unsigned short* wsw = (unsigned short*)(ws + WS_SWZ);
    int j    = idx & 7;
    int lane = (idx >> 3) & 63;
    int rem  = idx >> 9;
    int ks   = rem % 6;
    int nt   = (rem / 6) % 6;
    int mat  = rem / 36;
    int p = nt*16 + (lane & 15);
    int l = ks*32 + ((lane >> 4) & 3)*8 + j;
    float v = 0.f;
    if (l < SEQL) v = mat ? oma * tW[p*SEQL + l] : sW[p*SEQL + l];
    wsw[idx] = f2bf(v);
}

// ---------------------------------------------------------------- quantum feats
// Lane-parallel: 16 lanes per (b,circ) unit, one amplitude per lane.
__global__ void k_quantum(const float* __restrict__ x,
                          const float* __restrict__ lagc_W,
                          const float* __restrict__ lagc_b,
                          const float* __restrict__ ws,
                          float* __restrict__ feats)
{
    int tid  = blockIdx.x * blockDim.x + threadIdx.x;
    int unit = tid >> 4;          // (b, circ)
    int amp  = tid & 15;          // amplitude index, bit (3-q) per qubit q
    int b = unit / 3, circ = unit - b*3;

    const int LAGS[NLAG] = {167,166,165,164,163,162,145,144,143,1,0};
    const float* xb = x + (size_t)b*SEQL*CF + (CF-1);
    float lag[NLAG];
    #pragma unroll
    for (int j = 0; j < NLAG; ++j) lag[j] = xb[LAGS[j]*CF];

    float cq[4], sq[4];
    #pragma unroll
    for (int q = 0; q < 4; ++q) {
        float acc = lagc_b[q];
        #pragma unroll
        for (int j = 0; j < NLAG; ++j) acc = fmaf(lag[j], lagc_W[q*NLAG + j], acc);
        float half = 0.5f * 3.14159265358979323846f * tanhf(acc);
        cq[q] = cosf(half); sq[q] = sinf(half);
    }

    float sr = (amp == 0) ? 1.f : 0.f;
    float si = 0.f;

    const float* Ub = ws + WS_U + circ*96;

    for (int layer = 0; layer < 3; ++layer) {
        // RY(input) on each qubit
        #pragma unroll
        for (int q = 0; q < 4; ++q) {
            int m = 1 << (3-q);
            float pr  = __shfl_xor(sr, m);
            float pii = __shfl_xor(si, m);
            float sel = (amp & m) ? sq[q] : -sq[q];
            sr = fmaf(sel, pr,  cq[q]*sr);
            si = fmaf(sel, pii, cq[q]*si);
        }
        // Rot unitaries
        #pragma unroll
        for (int q = 0; q < 4; ++q) {
            const float* U = Ub + (layer*4 + q)*8;
            int m = 1 << (3-q);
            bool hi = (amp & m) != 0;
            float uar = hi ? U[6] : U[0];   // coeff on own amplitude
            float uai = hi ? U[7] : U[1];
            float ubr = hi ? U[4] : U[2];   // coeff on partner amplitude
            float ubi = hi ? U[5] : U[3];
            float pr  = __shfl_xor(sr, m);
            float pii = __shfl_xor(si, m);
            float nr = uar*sr - uai*si + ubr*pr - ubi*pii;
            float ni = uar*si + uai*sr + ubr*pii + ubi*pr;
            sr = nr; si = ni;
        }
        // CNOT ring
        #pragma unroll
        for (int q = 0; q < 4; ++q) {
            int t  = (q+1) & 3;
            int cm = 1 << (3-q), tm = 1 << (3-t);
            float pr  = __shfl_xor(sr, tm);
            float pii = __shfl_xor(si, tm);
            if (amp & cm) { sr = pr; si = pii; }
        }
    }

    // expvals: per-lane contribution, butterfly-reduce over the 16-lane unit
    #pragma unroll
    for (int q = 0; q < 4; ++q) {
        int m = 1 << (3-q);
        float pr  = __shfl_xor(sr, m);
        float pii = __shfl_xor(si, m);
        float v;
        if (circ == 0) {                       // X
            v = sr*pr + si*pii;
        } else if (circ == 1) {                // Y
            float t = sr*pii - si*pr;
            v = (amp & m) ? -t : t;
        } else {                               // Z
            float t = sr*sr + si*si;
            v = (amp & m) ? -t : t;
        }
        v += __shfl_xor(v, 1);
        v += __shfl_xor(v, 2);
        v += __shfl_xor(v, 4);
        v += __shfl_xor(v, 8);
        if (amp == 0) feats[b*12 + circ*4 + q] = v;
    }
}

// ---------------------------------------------------------------- fused conv+GEMM (MFMA)
// 1 block = 1 batch row, 256 threads = 4 waves.
// Phase A: sliding-window conv, bf16 T/S to LDS transposed [c][l] (stride 178).
// Phase B: wave wid -> (matrix = wid>>1, p-half = wid&1): each B fragment read ONCE
// per block (73.7 KB vs 295 KB) — kills the L1-thrash on the weight table.
// Trend waves deposit accT in LDS (overlaid on dead conv buffer); seasonal waves
// combine fs*S + T + cb and store.
__launch_bounds__(256, 3)
__global__ void k_gemm(const float* __restrict__ x,
                       const float* __restrict__ ws,
                       const float* __restrict__ seas_b,
                       const float* __restrict__ trend_b,
                       const float* __restrict__ roW1,
                       const float* __restrict__ rob1,
                       const float* __restrict__ roW2,
                       const float* __restrict__ rob2,
                       const float* __restrict__ alpha,
                       float* __restrict__ out)
{
    __shared__ __align__(16) unsigned short lbuf[2*64*LSTR + 64];   // T | S | slack
    __shared__ float fsL[PREDN];
    __shared__ float cbL[PREDN];

    int b = blockIdx.x;
    int tid = threadIdx.x;

    float a_sig = 1.f / (1.f + expf(-alpha[0]));
    float oma   = 1.f - a_sig;

    // readout MLP -> fs[p], cb[p]
    if (tid < PREDN) {
        const float* f = ws + WS_FEATS + b*12;
        float h[12];
        #pragma unroll
        for (int i = 0; i < 12; ++i) {
            float acc = rob1[i];
            #pragma unroll
            for (int j = 0; j < 12; ++j) acc = fmaf(roW1[i*12+j], f[j], acc);
            h[i] = fmaxf(acc, 0.f);
        }
        float acc = rob2[tid];
        #pragma unroll
        for (int i = 0; i < 12; ++i) acc = fmaf(roW2[tid*12+i], h[i], acc);
        float m   = tanhf(acc);
        float fsv = a_sig * (1.f + m);
        fsL[tid] = fsv;
        cbL[tid] = fsv*seas_b[tid] + oma*trend_b[tid];
    }

    // zero the LDS tail (l in [168,178) for every row, both arrays, + slack):
    // fragment reads touch those slots; B is zero there, values just must be finite.
    for (int i = tid; i < 2*64*10 + 64; i += 256) {
        if (i < 2*64*10) {
            int arr = i / 640;
            int rem = i - arr*640;
            int c   = rem / 10;
            int l   = 168 + rem - c*10;
            lbuf[arr*64*LSTR + c*LSTR + l] = 0;
        } else {
            lbuf[2*64*LSTR + (i - 2*64*10)] = 0;
        }
    }

    // ---- Phase A: sliding-window conv. thread -> (c = tid&63, seg = tid>>6) ----
    {
        int c   = tid & 63;
        int seg = tid >> 6;
        float cf[KK];
        #pragma unroll
        for (int k = 0; k < KK; ++k) cf[k] = ws[WS_KER + c*KK + k];
        const float* xc = x + (size_t)b*SEQL*CF + c;
        unsigned short* lT = lbuf + c*LSTR;
        unsigned short* lS = lbuf + 64*LSTR + c*LSTR;

        int l0 = seg*42;
        float w[KK];
        #pragma unroll
        for (int k = 0; k < KK; ++k) {           // preload window for l = l0 (edge-clamped)
            int ix = l0 + k - 12;
            ix = ix < 0 ? 0 : (ix > SEQL-1 ? SEQL-1 : ix);
            w[k] = xc[ix*CF];
        }
        #pragma unroll
        for (int l = 0; l < 42; ++l) {
            int ll = l0 + l;
            float acc = 0.f;
            #pragma unroll
            for (int k = 0; k < KK; ++k) acc = fmaf(cf[k], w[k], acc);
            lT[ll] = f2bf(acc);
            lS[ll] = f2bf(w[12] - acc);
            #pragma unroll
            for (int k = 0; k < KK-1; ++k) w[k] = w[k+1];   // SSA-renamed, no moves
            int ix = ll + 13;
            ix = ix > SEQL-1 ? SEQL-1 : ix;
            w[KK-1] = xc[ix*CF];
        }
    }
    __syncthreads();

    // ---- Phase B: MFMA GEMM. wave wid -> (mat = wid>>1, p-half = wid&1) ----
    int lane = tid & 63;
    int wid  = tid >> 6;
    int mrow = lane & 15;
    int q    = lane >> 4;
    int matT = wid >> 1;          // 0 = seasonal, 1 = trend
    int ntb  = (wid & 1)*3;       // p-tile base (3 tiles of 16)

    const unsigned int* L32 = (const unsigned int*)lbuf;
    const int SOFF = 64*LSTR/2;               // dword offset of S array (T is first)
    const int AOFF = matT ? 0 : SOFF;         // seasonal pairs with S, trend with T
    const unsigned short* wsw = (const unsigned short*)(ws + WS_SWZ);

    f32x4 acc[3][4];
    #pragma unroll
    for (int n3 = 0; n3 < 3; ++n3)
        #pragma unroll
        for (int ct = 0; ct < 4; ++ct)
            acc[n3][ct] = (f32x4){0.f,0.f,0.f,0.f};

    for (int ks = 0; ks < 6; ++ks) {
        short8 a[4];
        #pragma unroll
        for (int ct = 0; ct < 4; ++ct) {
            int ai = AOFF + (ct*16 + mrow)*(LSTR/2) + ks*16 + q*4;
            union { unsigned int u[4]; short8 v; } ua;
            #pragma unroll
            for (int d = 0; d < 4; ++d) ua.u[d] = L32[ai + d];
            a[ct] = ua.v;
        }
        #pragma unroll
        for (int n3 = 0; n3 < 3; ++n3) {
            short8 Bv = *(const short8*)(wsw + (((matT*6 + ntb + n3)*6 + ks)*64 + lane)*8);
            #pragma unroll
            for (int ct = 0; ct < 4; ++ct)
                acc[n3][ct] = __builtin_amdgcn_mfma_f32_16x16x32_bf16(a[ct], Bv, acc[n3][ct], 0, 0, 0);
        }
    }

    // ---- cross-wave combine: trend waves deposit, seasonal waves store ----
    __syncthreads();                          // all waves done reading lbuf
    float* tbuf = (float*)lbuf;               // overlay: [idx48][128] , idx = (n3*4+ct)*4+r
    if (matT) {
        int half = wid & 1;
        #pragma unroll
        for (int n3 = 0; n3 < 3; ++n3)
            #pragma unroll
            for (int ct = 0; ct < 4; ++ct)
                #pragma unroll
                for (int r = 0; r < 4; ++r)
                    tbuf[((n3*4+ct)*4+r)*128 + half*64 + lane] = acc[n3][ct][r];
    }
    __syncthreads();
    if (!matT) {
        #pragma unroll
        for (int n3 = 0; n3 < 3; ++n3) {
            int p = (ntb + n3)*16 + mrow;
            float fsv = fsL[p];
            float cbv = cbL[p];
            #pragma unroll
            for (int ct = 0; ct < 4; ++ct) {
                float* og = out + (size_t)b*PREDN*CF + p*CF + ct*16 + (q<<2);
                f32x4 r;
                #pragma unroll
                for (int r4 = 0; r4 < 4; ++r4) {
                    float tv = tbuf[((n3*4+ct)*4+r4)*128 + wid*64 + lane];
                    r[r4] = fmaf(fsv, acc[n3][ct][r4], tv + cbv);
                }
                *(f32x4*)og = r;
            }
        }
    }
}

// ---------------------------------------------------------------- launch
extern "C" void kernel_launch(void* const* d_in, const int* in_sizes, int n_in,
                              void* d_out, int out_size, void* d_ws, size_t ws_size,
                              hipStream_t stream)
{
    const float* x        = (const float*)d_in[0];
    const float* decomp_w = (const float*)d_in[1];
    const float* trend_W  = (const float*)d_in[2];
    const float* trend_b  = (const float*)d_in[3];
    const float* seas_W   = (const float*)d_in[4];
    const float* seas_b   = (const float*)d_in[5];
    const float* lagc_W   = (const float*)d_in[6];
    const float* lagc_b   = (const float*)d_in[7];
    const float* res_wx   = (const float*)d_in[8];
    const float* res_wy   = (const float*)d_in[9];
    const float* res_wz   = (const float*)d_in[10];
    const float* ro_W1    = (const float*)d_in[11];
    const float* ro_b1    = (const float*)d_in[12];
    const float* ro_W2    = (const float*)d_in[13];
    const float* ro_b2    = (const float*)d_in[14];
    const float* alpha    = (const float*)d_in[15];
    float* out = (float*)d_out;
    float* ws  = (float*)d_ws;

    k_pre<<<1, 128, 0, stream>>>(decomp_w, res_wx, res_wy, res_wz, ws);
    k_swz<<<144, 256, 0, stream>>>(seas_W, trend_W, alpha, ws);
    k_quantum<<<768, 256, 0, stream>>>(x, lagc_W, lagc_b, ws, ws + WS_FEATS);
    k_gemm<<<BB, 256, 0, stream>>>(x, ws, seas_b, trend_b,
                                   ro_W1, ro_b1, ro_W2, ro_b2, alpha, out);
}